// Round 2
// baseline (289.635 us; speedup 1.0000x reference)
//
#include <hip/hip_runtime.h>
#include <hip/hip_bf16.h>
#include <stdint.h>

// BlockedMLP: out = relu(bsr(relu(x@w1.T+b1))) @ w3.T + b3
// B=4096, D_IN=1024, H=4096, D_OUT=1024, BS=64

typedef __attribute__((ext_vector_type(4))) float f32x4;
typedef __attribute__((ext_vector_type(8))) __bf16 bf16x8;

#define DEV static __device__ __forceinline__

DEV ushort f2bf(float f) {
  union { float f; uint32_t u; } v; v.f = f;
  uint32_t r = v.u + 0x7fffu + ((v.u >> 16) & 1u);  // RNE
  return (ushort)(r >> 16);
}

DEV void gld_lds16(const void* g, void* l) {
  // async global->LDS, 16B/lane; LDS dest = wave-uniform base + lane*16
  __builtin_amdgcn_global_load_lds(
      (const __attribute__((address_space(1))) void*)g,
      (__attribute__((address_space(3))) void*)l, 16, 0, 0);
}

__global__ void cvt_kernel(const float* __restrict__ in, ushort* __restrict__ out, int n) {
  int i = (blockIdx.x * blockDim.x + threadIdx.x) * 4;
  if (i >= n) return;
  float4 v = *(const float4*)(in + i);
  ushort4 o;
  o.x = f2bf(v.x); o.y = f2bf(v.y); o.z = f2bf(v.z); o.w = f2bf(v.w);
  *(ushort4*)(out + i) = o;
}

// ---------------- dense GEMM (m97-structure, unchanged from R1) ----------------
template <bool RELU, bool OUT_BF16>
__global__ __launch_bounds__(256)
void gemm_nt(const ushort* __restrict__ A, const ushort* __restrict__ W,
             const float* __restrict__ bias, void* __restrict__ Cv,
             int K, int lda, int ldw, int ldc) {
  __shared__ ushort As[128 * 64];
  __shared__ ushort Ws[128 * 64];
  const int tid = threadIdx.x;
  const int wid = tid >> 6, lane = tid & 63;
  const int wm = wid >> 1, wn = wid & 1;
  const int i0 = blockIdx.y * 128, j0 = blockIdx.x * 128;
  f32x4 acc[4][4] = {};

  const int lrow = lane >> 3;
  const int lcol = (lane & 7) * 16;

  for (int k0 = 0; k0 < K; k0 += 64) {
#pragma unroll
    for (int i = 0; i < 4; ++i) {
      int ch = wid * 4 + i;
      int row = ch * 8 + lrow;
      const char* ga = (const char*)A + ((size_t)(i0 + row) * lda + k0) * 2 + lcol;
      gld_lds16(ga, (char*)As + ch * 1024);
      const char* gw = (const char*)W + ((size_t)(j0 + row) * ldw + k0) * 2 + lcol;
      gld_lds16(gw, (char*)Ws + ch * 1024);
    }
    __syncthreads();
#pragma unroll
    for (int kk = 0; kk < 64; kk += 32) {
      const int cl = lane & 15;
      const int kg = kk + (lane >> 4) * 8;
      bf16x8 a[4], b[4];
#pragma unroll
      for (int m = 0; m < 4; ++m)
        a[m] = *(const bf16x8*)&As[(wm * 64 + m * 16 + cl) * 64 + kg];
#pragma unroll
      for (int n = 0; n < 4; ++n)
        b[n] = *(const bf16x8*)&Ws[(wn * 64 + n * 16 + cl) * 64 + kg];
#pragma unroll
      for (int m = 0; m < 4; ++m)
#pragma unroll
        for (int n = 0; n < 4; ++n)
          acc[m][n] = __builtin_amdgcn_mfma_f32_16x16x32_bf16(a[m], b[n], acc[m][n], 0, 0, 0);
    }
    __syncthreads();
  }

  const int cl = lane & 15, r4 = (lane >> 4) * 4;
#pragma unroll
  for (int n = 0; n < 4; ++n) {
    int col = j0 + wn * 64 + n * 16 + cl;
    float bv = bias ? bias[col] : 0.0f;
#pragma unroll
    for (int m = 0; m < 4; ++m) {
      int rowb = i0 + wm * 64 + m * 16 + r4;
#pragma unroll
      for (int r = 0; r < 4; ++r) {
        float v = acc[m][n][r] + bv;
        if (RELU) v = fmaxf(v, 0.0f);
        if (OUT_BF16)
          ((ushort*)Cv)[(size_t)(rowb + r) * ldc + col] = f2bf(v);
        else
          ((float*)Cv)[(size_t)(rowb + r) * ldc + col] = v;
      }
    }
  }
}

// ---------------- BSR GEMM v2: pipelined dbuf + T2 swizzle + XCD chunk ----------------
// h2[:, br*64:+64] = relu( sum_{n in row br} h1[:, col[n]*64:+64] @ values[n]^T )
// 256x64 tile, 4 waves stacked in M (64x64 each, 4x4 frags).
// LDS: double-buffered A (2x32KB) + V (2x8KB) = 80KB -> 2 blocks/CU.
// Swizzle: 16B granule g of row r stored at granule g^(r&7); staging pre-swizzles
// the GLOBAL source (LDS dest stays linear for global_load_lds), reads XOR back.
__global__ __launch_bounds__(256)
void bsr_gemm(const ushort* __restrict__ A, const ushort* __restrict__ V,
              const int* __restrict__ crow, const int* __restrict__ colind,
              ushort* __restrict__ C, int Hdim) {
  __shared__ ushort As[2][256 * 64];  // 2 x 32KB
  __shared__ ushort Vs[2][64 * 64];   // 2 x 8KB
  const int tid = threadIdx.x;
  const int wid = tid >> 6, lane = tid & 63;

  // XCD-chunked mapping: grid 1024 = 8 XCDs x (8 block-rows x 16 batch tiles).
  // Each XCD's V working set = 8 rows x ~33 blk x 8KB ~= 2.1MB -> fits 4MB L2.
  const int bid = blockIdx.x;
  const int xcd = bid & 7, local = bid >> 3;
  const int br = xcd * 8 + (local >> 4);
  const int i0 = (local & 15) * 256;

  f32x4 acc[4][4] = {};
  const int n0 = crow[br], n1 = crow[br + 1];

  const int lr = lane >> 3;                       // 0..7 row-in-chunk
  const int gsw = ((lane & 7) ^ lr) * 16;         // pre-swizzled source granule byte

  auto stage = [&](int buf, int n) {
    const int c = colind[n];
    const char* Abase = (const char*)A + ((size_t)i0 * Hdim + (size_t)c * 64) * 2;
#pragma unroll
    for (int i = 0; i < 8; ++i) {
      int ch = wid * 8 + i;
      int row = ch * 8 + lr;  // 0..255
      gld_lds16(Abase + (size_t)row * Hdim * 2 + gsw, (char*)As[buf] + ch * 1024);
    }
    const char* Vbase = (const char*)V + (size_t)n * 8192;
#pragma unroll
    for (int i = 0; i < 2; ++i) {
      int ch = wid * 2 + i;
      int row = ch * 8 + lr;  // 0..63
      gld_lds16(Vbase + row * 128 + gsw, (char*)Vs[buf] + ch * 1024);
    }
  };

  auto compute = [&](int buf) {
#pragma unroll
    for (int kk = 0; kk < 64; kk += 32) {
      const int cl = lane & 15;
      const int kg = kk + (lane >> 4) * 8;
      const int kx = kg ^ ((cl & 7) << 3);  // row&7 == cl&7 for all our rows
      bf16x8 a[4], b[4];
#pragma unroll
      for (int m = 0; m < 4; ++m) {
        int row = wid * 64 + m * 16 + cl;
        a[m] = *(const bf16x8*)&As[buf][row * 64 + kx];
      }
#pragma unroll
      for (int nn = 0; nn < 4; ++nn) {
        int row = nn * 16 + cl;
        b[nn] = *(const bf16x8*)&Vs[buf][row * 64 + kx];
      }
      __builtin_amdgcn_s_setprio(1);
#pragma unroll
      for (int m = 0; m < 4; ++m)
#pragma unroll
        for (int nn = 0; nn < 4; ++nn)
          acc[m][nn] = __builtin_amdgcn_mfma_f32_16x16x32_bf16(a[m], b[nn], acc[m][nn], 0, 0, 0);
      __builtin_amdgcn_s_setprio(0);
    }
  };

  int cur = 0;
  stage(0, n0);
  __syncthreads();  // compiler drains vmcnt before s_barrier
  for (int n = n0; n < n1; ++n) {
    if (n + 1 < n1) stage(cur ^ 1, n + 1);  // prefetch next block while computing
    compute(cur);
    __syncthreads();  // drains vmcnt -> buf^1 staged; ds_reads of buf done
    cur ^= 1;
  }

  const int cl = lane & 15, r4 = (lane >> 4) * 4;
#pragma unroll
  for (int nn = 0; nn < 4; ++nn) {
    int col = br * 64 + nn * 16 + cl;
#pragma unroll
    for (int m = 0; m < 4; ++m) {
      int rowb = i0 + wid * 64 + m * 16 + r4;
#pragma unroll
      for (int r = 0; r < 4; ++r) {
        float v = fmaxf(acc[m][nn][r], 0.0f);
        C[(size_t)(rowb + r) * Hdim + col] = f2bf(v);
      }
    }
  }
}

extern "C" void kernel_launch(void* const* d_in, const int* in_sizes, int n_in,
                              void* d_out, int out_size, void* d_ws, size_t ws_size,
                              hipStream_t stream) {
  const float* x    = (const float*)d_in[0];
  const float* w1   = (const float*)d_in[1];
  const float* b1   = (const float*)d_in[2];
  const float* vals = (const float*)d_in[3];
  const float* w3   = (const float*)d_in[4];
  const float* b3   = (const float*)d_in[5];
  const int* crow   = (const int*)d_in[6];
  const int* colind = (const int*)d_in[7];

  const int Bb = 4096, Din = 1024, H = 4096, Dout = 1024;
  const int nnzb = in_sizes[7];

  char* ws = (char*)d_ws;
  ushort* xb  = (ushort*)ws; ws += (size_t)Bb * Din * 2;
  ushort* w1b = (ushort*)ws; ws += (size_t)H * Din * 2;
  ushort* w3b = (ushort*)ws; ws += (size_t)Dout * H * 2;
  ushort* vb  = (ushort*)ws; ws += (size_t)nnzb * 64 * 64 * 2;
  ushort* h1b = (ushort*)ws; ws += (size_t)Bb * H * 2;
  ushort* h2b = (ushort*)ws; ws += (size_t)Bb * H * 2;

  auto cvt = [&](const float* src, ushort* dst, size_t n) {
    int blocks = (int)((n / 4 + 255) / 256);
    hipLaunchKernelGGL(cvt_kernel, dim3(blocks), dim3(256), 0, stream, src, dst, (int)n);
  };
  cvt(x, xb, (size_t)Bb * Din);
  cvt(w1, w1b, (size_t)H * Din);
  cvt(w3, w3b, (size_t)Dout * H);
  cvt(vals, vb, (size_t)nnzb * 4096);

  // stage 1: h1 = relu(x @ w1^T + b1)   [4096 x 4096] bf16
  hipLaunchKernelGGL((gemm_nt<true, true>), dim3(H / 128, Bb / 128), dim3(256), 0, stream,
                     xb, w1b, b1, (void*)h1b, Din, Din, Din, H);
  // stage 2: h2 = relu(bsr(h1))         [4096 x 4096] bf16
  hipLaunchKernelGGL(bsr_gemm, dim3((Bb / 256) * (H / 64)), dim3(256), 0, stream,
                     h1b, vb, crow, colind, h2b, H);
  // stage 3: out = h2 @ w3^T + b3       [4096 x 1024] f32
  hipLaunchKernelGGL((gemm_nt<false, false>), dim3(Dout / 128, Bb / 128), dim3(256), 0, stream,
                     h2b, w3b, b3, d_out, H, H, H, Dout);
}

// Round 3
// 252.746 us; speedup vs baseline: 1.1460x; 1.1460x over previous
//
#include <hip/hip_runtime.h>
#include <hip/hip_bf16.h>
#include <stdint.h>

// BlockedMLP: out = relu(bsr(relu(x@w1.T+b1))) @ w3.T + b3
// B=4096, D_IN=1024, H=4096, D_OUT=1024, BS=64

typedef __attribute__((ext_vector_type(4))) float f32x4;
typedef __attribute__((ext_vector_type(8))) __bf16 bf16x8;

#define DEV static __device__ __forceinline__

DEV ushort f2bf(float f) {
  union { float f; uint32_t u; } v; v.f = f;
  uint32_t r = v.u + 0x7fffu + ((v.u >> 16) & 1u);  // RNE
  return (ushort)(r >> 16);
}

DEV void gld_lds16(const void* g, void* l) {
  // async global->LDS, 16B/lane; LDS dest = wave-uniform base + lane*16
  __builtin_amdgcn_global_load_lds(
      (const __attribute__((address_space(1))) void*)g,
      (__attribute__((address_space(3))) void*)l, 16, 0, 0);
}

__global__ void cvt_kernel(const float* __restrict__ in, ushort* __restrict__ out, int n) {
  int i = (blockIdx.x * blockDim.x + threadIdx.x) * 4;
  if (i >= n) return;
  float4 v = *(const float4*)(in + i);
  ushort4 o;
  o.x = f2bf(v.x); o.y = f2bf(v.y); o.z = f2bf(v.z); o.w = f2bf(v.w);
  *(ushort4*)(out + i) = o;
}

// ---------------- dense GEMM (m97-structure, unchanged) ----------------
template <bool RELU, bool OUT_BF16>
__global__ __launch_bounds__(256)
void gemm_nt(const ushort* __restrict__ A, const ushort* __restrict__ W,
             const float* __restrict__ bias, void* __restrict__ Cv,
             int K, int lda, int ldw, int ldc) {
  __shared__ ushort As[128 * 64];
  __shared__ ushort Ws[128 * 64];
  const int tid = threadIdx.x;
  const int wid = tid >> 6, lane = tid & 63;
  const int wm = wid >> 1, wn = wid & 1;
  const int i0 = blockIdx.y * 128, j0 = blockIdx.x * 128;
  f32x4 acc[4][4] = {};

  const int lrow = lane >> 3;
  const int lcol = (lane & 7) * 16;

  for (int k0 = 0; k0 < K; k0 += 64) {
#pragma unroll
    for (int i = 0; i < 4; ++i) {
      int ch = wid * 4 + i;
      int row = ch * 8 + lrow;
      const char* ga = (const char*)A + ((size_t)(i0 + row) * lda + k0) * 2 + lcol;
      gld_lds16(ga, (char*)As + ch * 1024);
      const char* gw = (const char*)W + ((size_t)(j0 + row) * ldw + k0) * 2 + lcol;
      gld_lds16(gw, (char*)Ws + ch * 1024);
    }
    __syncthreads();
#pragma unroll
    for (int kk = 0; kk < 64; kk += 32) {
      const int cl = lane & 15;
      const int kg = kk + (lane >> 4) * 8;
      bf16x8 a[4], b[4];
#pragma unroll
      for (int m = 0; m < 4; ++m)
        a[m] = *(const bf16x8*)&As[(wm * 64 + m * 16 + cl) * 64 + kg];
#pragma unroll
      for (int n = 0; n < 4; ++n)
        b[n] = *(const bf16x8*)&Ws[(wn * 64 + n * 16 + cl) * 64 + kg];
#pragma unroll
      for (int m = 0; m < 4; ++m)
#pragma unroll
        for (int n = 0; n < 4; ++n)
          acc[m][n] = __builtin_amdgcn_mfma_f32_16x16x32_bf16(a[m], b[n], acc[m][n], 0, 0, 0);
    }
    __syncthreads();
  }

  const int cl = lane & 15, r4 = (lane >> 4) * 4;
#pragma unroll
  for (int n = 0; n < 4; ++n) {
    int col = j0 + wn * 64 + n * 16 + cl;
    float bv = bias ? bias[col] : 0.0f;
#pragma unroll
    for (int m = 0; m < 4; ++m) {
      int rowb = i0 + wm * 64 + m * 16 + r4;
#pragma unroll
      for (int r = 0; r < 4; ++r) {
        float v = acc[m][n][r] + bv;
        if (RELU) v = fmaxf(v, 0.0f);
        if (OUT_BF16)
          ((ushort*)Cv)[(size_t)(rowb + r) * ldc + col] = f2bf(v);
        else
          ((float*)Cv)[(size_t)(rowb + r) * ldc + col] = v;
      }
    }
  }
}

// ---------------- BSR GEMM v3: dbuf + swizzle + TILE-pinned XCD mapping ----------------
// h2[:, br*64:+64] = relu( sum_{n in row br} h1[:, col[n]*64:+64] @ values[n]^T )
// 256x64 tile, 4 waves stacked in M (64x64 each, 4x4 frags).
// LDS: double-buffered A (2x32KB) + V (2x8KB) = 80KB -> 2 blocks/CU.
// XCD mapping: XCD k is pinned to batch tiles {k, k+8} for ALL block-rows
// (br-major order). Per-XCD concurrent A slice = 2 tiles x 256 rows x 4096
// cols x 2B = 4MB -> fits per-XCD L2; V blocks reused by both resident tiles.
__global__ __launch_bounds__(256)
void bsr_gemm(const ushort* __restrict__ A, const ushort* __restrict__ V,
              const int* __restrict__ crow, const int* __restrict__ colind,
              ushort* __restrict__ C, int Hdim) {
  __shared__ ushort As[2][256 * 64];  // 2 x 32KB
  __shared__ ushort Vs[2][64 * 64];   // 2 x 8KB
  const int tid = threadIdx.x;
  const int wid = tid >> 6, lane = tid & 63;

  const int bid = blockIdx.x;         // 0..1023
  const int xcd = bid & 7;
  const int j = bid >> 3;             // 0..127
  const int tile = xcd + 8 * (j & 1); // XCD k owns tiles {k, k+8}
  const int br = j >> 1;              // 0..63, br-major
  const int i0 = tile * 256;

  f32x4 acc[4][4] = {};
  const int n0 = crow[br], n1 = crow[br + 1];

  const int lr = lane >> 3;                       // 0..7 row-in-chunk
  const int gsw = ((lane & 7) ^ lr) * 16;         // pre-swizzled source granule byte

  auto stage = [&](int buf, int n) {
    const int c = colind[n];
    const char* Abase = (const char*)A + ((size_t)i0 * Hdim + (size_t)c * 64) * 2;
#pragma unroll
    for (int i = 0; i < 8; ++i) {
      int ch = wid * 8 + i;
      int row = ch * 8 + lr;  // 0..255
      gld_lds16(Abase + (size_t)row * Hdim * 2 + gsw, (char*)As[buf] + ch * 1024);
    }
    const char* Vbase = (const char*)V + (size_t)n * 8192;
#pragma unroll
    for (int i = 0; i < 2; ++i) {
      int ch = wid * 2 + i;
      int row = ch * 8 + lr;  // 0..63
      gld_lds16(Vbase + row * 128 + gsw, (char*)Vs[buf] + ch * 1024);
    }
  };

  auto compute = [&](int buf) {
#pragma unroll
    for (int kk = 0; kk < 64; kk += 32) {
      const int cl = lane & 15;
      const int kg = kk + (lane >> 4) * 8;
      const int kx = kg ^ ((cl & 7) << 3);  // row&7 == cl&7 for all our rows
      bf16x8 a[4], b[4];
#pragma unroll
      for (int m = 0; m < 4; ++m) {
        int row = wid * 64 + m * 16 + cl;
        a[m] = *(const bf16x8*)&As[buf][row * 64 + kx];
      }
#pragma unroll
      for (int nn = 0; nn < 4; ++nn) {
        int row = nn * 16 + cl;
        b[nn] = *(const bf16x8*)&Vs[buf][row * 64 + kx];
      }
      __builtin_amdgcn_s_setprio(1);
#pragma unroll
      for (int m = 0; m < 4; ++m)
#pragma unroll
        for (int nn = 0; nn < 4; ++nn)
          acc[m][nn] = __builtin_amdgcn_mfma_f32_16x16x32_bf16(a[m], b[nn], acc[m][nn], 0, 0, 0);
      __builtin_amdgcn_s_setprio(0);
    }
  };

  int cur = 0;
  stage(0, n0);
  __syncthreads();
  for (int n = n0; n < n1; ++n) {
    if (n + 1 < n1) stage(cur ^ 1, n + 1);  // prefetch next block while computing
    compute(cur);
    __syncthreads();
    cur ^= 1;
  }

  const int cl = lane & 15, r4 = (lane >> 4) * 4;
#pragma unroll
  for (int nn = 0; nn < 4; ++nn) {
    int col = br * 64 + nn * 16 + cl;
#pragma unroll
    for (int m = 0; m < 4; ++m) {
      int rowb = i0 + wid * 64 + m * 16 + r4;
#pragma unroll
      for (int r = 0; r < 4; ++r) {
        float v = fmaxf(acc[m][nn][r], 0.0f);
        C[(size_t)(rowb + r) * Hdim + col] = f2bf(v);
      }
    }
  }
}

extern "C" void kernel_launch(void* const* d_in, const int* in_sizes, int n_in,
                              void* d_out, int out_size, void* d_ws, size_t ws_size,
                              hipStream_t stream) {
  const float* x    = (const float*)d_in[0];
  const float* w1   = (const float*)d_in[1];
  const float* b1   = (const float*)d_in[2];
  const float* vals = (const float*)d_in[3];
  const float* w3   = (const float*)d_in[4];
  const float* b3   = (const float*)d_in[5];
  const int* crow   = (const int*)d_in[6];
  const int* colind = (const int*)d_in[7];

  const int Bb = 4096, Din = 1024, H = 4096, Dout = 1024;
  const int nnzb = in_sizes[7];

  char* ws = (char*)d_ws;
  ushort* xb  = (ushort*)ws; ws += (size_t)Bb * Din * 2;
  ushort* w1b = (ushort*)ws; ws += (size_t)H * Din * 2;
  ushort* w3b = (ushort*)ws; ws += (size_t)Dout * H * 2;
  ushort* vb  = (ushort*)ws; ws += (size_t)nnzb * 64 * 64 * 2;
  ushort* h1b = (ushort*)ws; ws += (size_t)Bb * H * 2;
  ushort* h2b = (ushort*)ws; ws += (size_t)Bb * H * 2;

  auto cvt = [&](const float* src, ushort* dst, size_t n) {
    int blocks = (int)((n / 4 + 255) / 256);
    hipLaunchKernelGGL(cvt_kernel, dim3(blocks), dim3(256), 0, stream, src, dst, (int)n);
  };
  cvt(x, xb, (size_t)Bb * Din);
  cvt(w1, w1b, (size_t)H * Din);
  cvt(w3, w3b, (size_t)Dout * H);
  cvt(vals, vb, (size_t)nnzb * 4096);

  // stage 1: h1 = relu(x @ w1^T + b1)   [4096 x 4096] bf16
  hipLaunchKernelGGL((gemm_nt<true, true>), dim3(H / 128, Bb / 128), dim3(256), 0, stream,
                     xb, w1b, b1, (void*)h1b, Din, Din, Din, H);
  // stage 2: h2 = relu(bsr(h1))         [4096 x 4096] bf16
  hipLaunchKernelGGL(bsr_gemm, dim3((Bb / 256) * (H / 64)), dim3(256), 0, stream,
                     h1b, vb, crow, colind, h2b, H);
  // stage 3: out = h2 @ w3^T + b3       [4096 x 1024] f32
  hipLaunchKernelGGL((gemm_nt<false, false>), dim3(Dout / 128, Bb / 128), dim3(256), 0, stream,
                     h2b, w3b, b3, d_out, H, H, H, Dout);
}